// Round 4
// baseline (303.093 us; speedup 1.0000x reference)
//
#include <hip/hip_runtime.h>

// TileWarping: B=4, C=16, H=512, W=960, UP=4 -> out [4, 48, 128, 240] f32.
// R3: barrier-free direct-gather. R0-R2 all plateaued at ~103us with every
// pipe <20% busy -> latency-bound on the staging->syncthreads(vmcnt(0) drain)
// ->consume chain. This version has NO LDS, NO barriers, NO DMA: per channel,
// gather the 4 bilinear taps straight from global (clamped exact addresses,
// weight-masked for OOB). 80 independent loads/thread = max MLP; wave-lane
// taps are consecutive-ish so L1 coalescing is good.
//  - k-trick kept: 3 disp_d variants share taps p..p+3, channel-invariant
//    masked weights.
//  - block = 320 threads (5 waves), grid (3, 512, 4): X = 320*s + t < 960
//    always, no tail masking.

#define NB 4
#define NC 16
#define NH 512
#define NW 960
#define TH 128
#define TW 240
#define HW (NH * NW)

__global__ __launch_bounds__(320) void tile_warp_kernel(
    const float* __restrict__ tp,   // [B,3,128,240]
    const float* __restrict__ fl,   // [B,16,512,960]
    const float* __restrict__ fr,   // [B,16,512,960]
    float* __restrict__ out)        // [B,48,128,240]
{
    const int t = threadIdx.x;      // 0..319
    const int s = blockIdx.x;       // 0..2
    const int Y = blockIdx.y;       // 0..511
    const int b = blockIdx.z;       // 0..3
    const int X = s * 320 + t;      // 0..959
    const int y = Y >> 2, i = Y & 3;
    const int j = X & 3, T = X >> 2;

    // per-thread warp geometry
    const int tpb = (b * 3 * TH + y) * TW + T;
    const float d   = tp[tpb];
    const float dxv = tp[tpb + TH * TW];
    const float dyv = tp[tpb + 2 * TH * TW];
    const float disp = d + ((float)i - 1.5f) * dyv + ((float)j - 1.5f) * dxv;
    const float xf  = (float)X - disp;         // disp_d = 0 variant
    const float x0f = floorf(xf);
    const float w1  = xf - x0f;
    const float w0  = 1.0f - w1;
    const int   p   = (int)x0f - 1;            // shared taps p..p+3

    const int t0 = min(max(p,     0), NW - 1);
    const int t1 = min(max(p + 1, 0), NW - 1);
    const int t2 = min(max(p + 2, 0), NW - 1);
    const int t3 = min(max(p + 3, 0), NW - 1);

    // channel-invariant masked weights for the 3 disp_d variants
    float w0k[3], w1k[3];
#pragma unroll
    for (int kk = 0; kk < 3; ++kk) {
        const int xa = p + 2 - kk;
        const int xb = xa + 1;
        w0k[kk] = (xa >= 0 && xa < NW) ? w0 : 0.0f;
        w1k[kk] = (xb >= 0 && xb < NW) ? w1 : 0.0f;
    }

    const float* frr = fr + (size_t)(b * NC) * HW + (size_t)Y * NW;
    const float* flr = fl + (size_t)(b * NC) * HW + (size_t)Y * NW + X;

    float a0 = 0.f, a1 = 0.f, a2 = 0.f;
#pragma unroll
    for (int c = 0; c < NC; ++c) {
        const float* R = frr + (size_t)c * HW;
        const float m0 = R[t0];
        const float m1 = R[t1];
        const float m2 = R[t2];
        const float m3 = R[t3];
        const float fv = flr[(size_t)c * HW];
        a0 += fabsf(fv - (m2 * w0k[0] + m3 * w1k[0]));
        a1 += fabsf(fv - (m1 * w0k[1] + m2 * w1k[1]));
        a2 += fabsf(fv - (m0 * w0k[2] + m1 * w1k[2]));
    }

    const size_t ob = ((size_t)(b * 48 + i * 4 + j) * TH + y) * TW + T;
    out[ob]                        = a0;
    out[ob + 16 * (size_t)TH * TW] = a1;
    out[ob + 32 * (size_t)TH * TW] = a2;
}

extern "C" void kernel_launch(void* const* d_in, const int* in_sizes, int n_in,
                              void* d_out, int out_size, void* d_ws, size_t ws_size,
                              hipStream_t stream) {
    const float* tp = (const float*)d_in[0];
    const float* fl = (const float*)d_in[1];
    const float* fr = (const float*)d_in[2];
    float* out = (float*)d_out;

    dim3 grid(3, NH, NB);   // 6144 blocks
    dim3 block(320);        // 5 waves, all threads active
    tile_warp_kernel<<<grid, block, 0, stream>>>(tp, fl, fr, out);
}